// Round 1
// baseline (691.129 us; speedup 1.0000x reference)
//
#include <hip/hip_runtime.h>

#define D 64

// grid-stride zero
__global__ void zero_f32(float* __restrict__ p, long n) {
    long i = (long)blockIdx.x * blockDim.x + threadIdx.x;
    long stride = (long)gridDim.x * blockDim.x;
    for (; i < n; i += stride) p[i] = 0.0f;
}

// deg[dst[e]] += 1
__global__ void deg_kernel(const int* __restrict__ dst, float* __restrict__ deg, int E) {
    int e = blockIdx.x * blockDim.x + threadIdx.x;
    if (e < E) unsafeAtomicAdd(&deg[dst[e]], 1.0f);
}

// in-place: deg -> norm = rsqrt(max(deg,1)); norm2 = norm*norm
__global__ void norm_kernel(float* __restrict__ deg_norm, float* __restrict__ norm2, int N) {
    int i = blockIdx.x * blockDim.x + threadIdx.x;
    if (i < N) {
        float d = deg_norm[i];
        d = d < 1.0f ? 1.0f : d;
        float r = rsqrtf(d);
        deg_norm[i] = r;
        norm2[i] = r * r;
    }
}

// one wave per edge, lane = feature index.
// out[dst*D + lane] += x[src*D + lane] * scale[src]
__global__ void scatter_kernel(const float* __restrict__ x,
                               const float* __restrict__ scale,
                               const int* __restrict__ src,
                               const int* __restrict__ dst,
                               float* __restrict__ out, int E) {
    long idx = (long)blockIdx.x * blockDim.x + threadIdx.x;
    int e = (int)(idx >> 6);
    int lane = (int)(idx & 63);
    if (e < E) {
        int s = src[e];
        int d0 = dst[e];
        float v = x[(long)s * D + lane] * scale[s];
        unsafeAtomicAdd(&out[(long)d0 * D + lane], v);
    }
}

// out[i] *= norm[i / D]
__global__ void scale_kernel(float* __restrict__ out, const float* __restrict__ norm, long n) {
    long i = (long)blockIdx.x * blockDim.x + threadIdx.x;
    if (i < n) out[i] *= norm[i >> 6];
}

extern "C" void kernel_launch(void* const* d_in, const int* in_sizes, int n_in,
                              void* d_out, int out_size, void* d_ws, size_t ws_size,
                              hipStream_t stream) {
    const float* feat = (const float*)d_in[0];
    const int*   src  = (const int*)d_in[1];
    const int*   dst  = (const int*)d_in[2];
    float* out = (float*)d_out;

    const int N = in_sizes[0] / D;   // 100000
    const int E = in_sizes[1];       // 1200000

    // ws layout: norm[N] | norm2[N] | buf1[N*D]
    float* norm  = (float*)d_ws;
    float* norm2 = norm + N;
    float* buf1  = norm2 + N;

    const long ND = (long)N * D;

    // 1. zero: whole ws stretch (2N + ND) and d_out (ND)
    {
        long nz = 2L * N + ND;
        int blocks = (int)((nz + 255) / 256);
        zero_f32<<<blocks, 256, 0, stream>>>((float*)d_ws, nz);
        blocks = (int)((ND + 255) / 256);
        zero_f32<<<blocks, 256, 0, stream>>>(out, ND);
    }

    // 2. degree
    deg_kernel<<<(E + 255) / 256, 256, 0, stream>>>(dst, norm, E);

    // 3. norm / norm^2
    norm_kernel<<<(N + 255) / 256, 256, 0, stream>>>(norm, norm2, N);

    // 4. hop 1: buf1 = S(norm ⊙ feat)
    {
        long work = (long)E * D;
        int blocks = (int)((work + 255) / 256);
        scatter_kernel<<<blocks, 256, 0, stream>>>(feat, norm, src, dst, buf1, E);
    }

    // 5. hop 2: out = S(norm^2 ⊙ buf1)
    {
        long work = (long)E * D;
        int blocks = (int)((work + 255) / 256);
        scatter_kernel<<<blocks, 256, 0, stream>>>(buf1, norm2, src, dst, out, E);
    }

    // 6. final post-scale: out *= norm
    {
        int blocks = (int)((ND + 255) / 256);
        scale_kernel<<<blocks, 256, 0, stream>>>(out, norm, ND);
    }
}

// Round 2
// 319.375 us; speedup vs baseline: 2.1640x; 2.1640x over previous
//
#include <hip/hip_runtime.h>

#define D 64
#define SCAN_B 512

// ---------------- shared small kernels ----------------

__global__ void zero_f32(float* __restrict__ p, long n) {
    long i = (long)blockIdx.x * blockDim.x + threadIdx.x;
    long stride = (long)gridDim.x * blockDim.x;
    for (; i < n; i += stride) p[i] = 0.0f;
}

__global__ void zero_i32(int* __restrict__ p, int n) {
    int i = blockIdx.x * blockDim.x + threadIdx.x;
    if (i < n) p[i] = 0;
}

// ---------------- CSR path ----------------

// deg[dst[e]] += 1  (int histogram)
__global__ void hist_kernel(const int* __restrict__ dst, int* __restrict__ deg, int E) {
    int e = blockIdx.x * blockDim.x + threadIdx.x;
    if (e < E) atomicAdd(&deg[dst[e]], 1);
}

// per-block exclusive scan of deg -> row_ptr (partial), blocksum -> bsum
__global__ void scanA_kernel(const int* __restrict__ deg, int* __restrict__ row_ptr,
                             int* __restrict__ bsum, int N) {
    __shared__ int s[SCAN_B];
    int tid = threadIdx.x;
    int i = blockIdx.x * SCAN_B + tid;
    int v = (i < N) ? deg[i] : 0;
    s[tid] = v;
    __syncthreads();
    for (int off = 1; off < SCAN_B; off <<= 1) {
        int t = (tid >= off) ? s[tid - off] : 0;
        __syncthreads();
        s[tid] += t;
        __syncthreads();
    }
    if (i < N) row_ptr[i] = s[tid] - v;        // exclusive
    if (tid == SCAN_B - 1) bsum[blockIdx.x] = s[tid];  // inclusive total
}

// single-block exclusive scan of bsum[nb], nb <= SCAN_B
__global__ void scanB_kernel(int* __restrict__ bsum, int nb) {
    __shared__ int s[SCAN_B];
    int tid = threadIdx.x;
    int v = (tid < nb) ? bsum[tid] : 0;
    s[tid] = v;
    __syncthreads();
    for (int off = 1; off < SCAN_B; off <<= 1) {
        int t = (tid >= off) ? s[tid - off] : 0;
        __syncthreads();
        s[tid] += t;
        __syncthreads();
    }
    if (tid < nb) bsum[tid] = s[tid] - v;      // exclusive
}

// row_ptr[i] += bsum[i/SCAN_B]; fill_ptr[i] = row_ptr[i]; row_ptr[N] = E
__global__ void scanC_kernel(int* __restrict__ row_ptr, int* __restrict__ fill_ptr,
                             const int* __restrict__ bsum, int N, int E) {
    int i = blockIdx.x * blockDim.x + threadIdx.x;
    if (i < N) {
        int r = row_ptr[i] + bsum[i / SCAN_B];
        row_ptr[i] = r;
        fill_ptr[i] = r;
    }
    if (i == 0) row_ptr[N] = E;
}

// norm from int deg
__global__ void norm_from_deg(const int* __restrict__ deg, float* __restrict__ norm,
                              float* __restrict__ norm2, int N) {
    int i = blockIdx.x * blockDim.x + threadIdx.x;
    if (i < N) {
        float d = (float)deg[i];
        d = d < 1.0f ? 1.0f : d;
        float r = rsqrtf(d);
        norm[i] = r;
        norm2[i] = r * r;
    }
}

// csr_src[atomicAdd(fill_ptr[dst[e]],1)] = src[e]
__global__ void fill_kernel(const int* __restrict__ src, const int* __restrict__ dst,
                            int* __restrict__ fill_ptr, int* __restrict__ csr_src, int E) {
    int e = blockIdx.x * blockDim.x + threadIdx.x;
    if (e < E) {
        int pos = atomicAdd(&fill_ptr[dst[e]], 1);
        csr_src[pos] = src[e];
    }
}

// pull-mode aggregation: one wave per node; lane group g=lane>>4 handles edge
// beg+g, beg+g+4, ...; 16 lanes x float4 cover the 64-float row.
// out[n] = postmul * sum_e scale[src_e] * x[src_e]
__global__ void gather_kernel(const float* __restrict__ x,
                              const float* __restrict__ scale,
                              const int* __restrict__ row_ptr,
                              const int* __restrict__ csr_src,
                              const float* __restrict__ post,   // nullptr -> 1.0
                              float* __restrict__ out, int N) {
    long idx = (long)blockIdx.x * blockDim.x + threadIdx.x;
    int w = (int)(idx >> 6);
    if (w >= N) return;
    int lane = (int)(idx & 63);
    int g = lane >> 4;
    int sub = lane & 15;
    int beg = row_ptr[w], end = row_ptr[w + 1];
    float ax = 0.f, ay = 0.f, az = 0.f, aw = 0.f;
    for (int e = beg + g; e < end; e += 4) {
        int s = csr_src[e];
        float sc = scale[s];
        const float4* p = (const float4*)(x + (long)s * D) + sub;
        float4 v = *p;
        ax += v.x * sc; ay += v.y * sc; az += v.z * sc; aw += v.w * sc;
    }
    // combine the 4 lane-groups (each holds a partial sum of the same row slice)
    ax += __shfl_xor(ax, 16, 64); ay += __shfl_xor(ay, 16, 64);
    az += __shfl_xor(az, 16, 64); aw += __shfl_xor(aw, 16, 64);
    ax += __shfl_xor(ax, 32, 64); ay += __shfl_xor(ay, 32, 64);
    az += __shfl_xor(az, 32, 64); aw += __shfl_xor(aw, 32, 64);
    if (g == 0) {
        float pn = post ? post[w] : 1.0f;
        float4 r; r.x = ax * pn; r.y = ay * pn; r.z = az * pn; r.w = aw * pn;
        ((float4*)(out + (long)w * D))[sub] = r;
    }
}

// ---------------- fallback (round-1 atomic push) ----------------

__global__ void deg_kernel_f(const int* __restrict__ dst, float* __restrict__ deg, int E) {
    int e = blockIdx.x * blockDim.x + threadIdx.x;
    if (e < E) unsafeAtomicAdd(&deg[dst[e]], 1.0f);
}

__global__ void norm_kernel_f(float* __restrict__ deg_norm, float* __restrict__ norm2, int N) {
    int i = blockIdx.x * blockDim.x + threadIdx.x;
    if (i < N) {
        float d = deg_norm[i];
        d = d < 1.0f ? 1.0f : d;
        float r = rsqrtf(d);
        deg_norm[i] = r;
        norm2[i] = r * r;
    }
}

__global__ void scatter_kernel(const float* __restrict__ x,
                               const float* __restrict__ scale,
                               const int* __restrict__ src,
                               const int* __restrict__ dst,
                               float* __restrict__ out, int E) {
    long idx = (long)blockIdx.x * blockDim.x + threadIdx.x;
    int e = (int)(idx >> 6);
    int lane = (int)(idx & 63);
    if (e < E) {
        int s = src[e];
        int d0 = dst[e];
        float v = x[(long)s * D + lane] * scale[s];
        unsafeAtomicAdd(&out[(long)d0 * D + lane], v);
    }
}

__global__ void scale_kernel(float* __restrict__ out, const float* __restrict__ norm, long n) {
    long i = (long)blockIdx.x * blockDim.x + threadIdx.x;
    if (i < n) out[i] *= norm[i >> 6];
}

// ---------------- launch ----------------

extern "C" void kernel_launch(void* const* d_in, const int* in_sizes, int n_in,
                              void* d_out, int out_size, void* d_ws, size_t ws_size,
                              hipStream_t stream) {
    const float* feat = (const float*)d_in[0];
    const int*   src  = (const int*)d_in[1];
    const int*   dst  = (const int*)d_in[2];
    float* out = (float*)d_out;

    const int N = in_sizes[0] / D;   // 100000
    const int E = in_sizes[1];       // 1200000
    const long ND = (long)N * D;

    // CSR-path ws layout (floats first for 16B alignment of buf1):
    //   norm[N] | norm2[N] | buf1[ND] | deg[N] | row_ptr[N+1] | fill_ptr[N] |
    //   bsum[SCAN_B] | csr_src[E]
    size_t need = (size_t)(2L * N + ND) * 4 +
                  (size_t)(3L * N + 1 + SCAN_B + E) * 4;

    if (ws_size >= need) {
        float* norm  = (float*)d_ws;
        float* norm2 = norm + N;
        float* buf1  = norm2 + N;
        int* deg      = (int*)(buf1 + ND);
        int* row_ptr  = deg + N;
        int* fill_ptr = row_ptr + N + 1;
        int* bsum     = fill_ptr + N;
        int* csr_src  = bsum + SCAN_B;

        int nb = (N + SCAN_B - 1) / SCAN_B;

        zero_i32<<<(N + 255) / 256, 256, 0, stream>>>(deg, N);
        hist_kernel<<<(E + 255) / 256, 256, 0, stream>>>(dst, deg, E);
        scanA_kernel<<<nb, SCAN_B, 0, stream>>>(deg, row_ptr, bsum, N);
        scanB_kernel<<<1, SCAN_B, 0, stream>>>(bsum, nb);
        scanC_kernel<<<(N + 255) / 256, 256, 0, stream>>>(row_ptr, fill_ptr, bsum, N, E);
        norm_from_deg<<<(N + 255) / 256, 256, 0, stream>>>(deg, norm, norm2, N);
        fill_kernel<<<(E + 255) / 256, 256, 0, stream>>>(src, dst, fill_ptr, csr_src, E);

        long thr = (long)N * 64;
        int blocks = (int)((thr + 255) / 256);
        // hop 1: buf1 = S(norm ⊙ feat)
        gather_kernel<<<blocks, 256, 0, stream>>>(feat, norm, row_ptr, csr_src,
                                                  nullptr, buf1, N);
        // hop 2: out = norm ⊙ S(norm2 ⊙ buf1)
        gather_kernel<<<blocks, 256, 0, stream>>>(buf1, norm2, row_ptr, csr_src,
                                                  norm, out, N);
    } else {
        // fallback: atomic push mode (round-1)
        float* norm  = (float*)d_ws;
        float* norm2 = norm + N;
        float* buf1  = norm2 + N;

        long nz = 2L * N + ND;
        zero_f32<<<(int)((nz + 255) / 256), 256, 0, stream>>>((float*)d_ws, nz);
        zero_f32<<<(int)((ND + 255) / 256), 256, 0, stream>>>(out, ND);
        deg_kernel_f<<<(E + 255) / 256, 256, 0, stream>>>(dst, norm, E);
        norm_kernel_f<<<(N + 255) / 256, 256, 0, stream>>>(norm, norm2, N);
        long work = (long)E * D;
        int blocks = (int)((work + 255) / 256);
        scatter_kernel<<<blocks, 256, 0, stream>>>(feat, norm, src, dst, buf1, E);
        scatter_kernel<<<blocks, 256, 0, stream>>>(buf1, norm2, src, dst, out, E);
        scale_kernel<<<(int)((ND + 255) / 256), 256, 0, stream>>>(out, norm, ND);
    }
}